// Round 1
// baseline (20770.865 us; speedup 1.0000x reference)
//
#include <hip/hip_runtime.h>
#include <hip/hip_bf16.h>

// ---------------- problem constants ----------------
#define TSEQ 512
#define NB   64
#define NE   256
#define NH   512
#define NG   2048   // 4*NH

// ---------------- workspace layout (bytes) ----------------
// W1 frag: 2 dir * 64 slice * 24 chunk * 2 tile * 64 lane * 8 elem * 2B = 6,291,456
// W2 frag: 2 * 64 * 32 * 2 * 64 * 8 * 2B                                = 8,388,608
// X bf16 [T][B][E]                                                      = 16,777,216
// h1 ring [dir][4][B][H] bf16                                           = 524,288
// h2 ring [dir][4][B][H] bf16                                           = 524,288
// h2 final [dir][B][H] bf16                                             = 131,072
// counters                                                              = 64
static const size_t OFF_W1  = 0;
static const size_t OFF_W2  = 6291456;
static const size_t OFF_X   = 14680064;
static const size_t OFF_H1  = 31457280;
static const size_t OFF_H2  = 31981568;
static const size_t OFF_HF  = 32505856;
static const size_t OFF_CNT = 32636928;

typedef __bf16 v8bf __attribute__((ext_vector_type(8)));
typedef float  v4f  __attribute__((ext_vector_type(4)));

#define MFMA16(a_, b_, c_) __builtin_amdgcn_mfma_f32_16x16x32_bf16((a_), (b_), (c_), 0, 0, 0)

// ---------------- phase A: weight convert to fragment-linear bf16 ----------------
// dst element id = ((((dir*64+slice)*NC + c)*2 + t)*64 + lane)*8 + j
// holds B[k = c*32 + (lane>>4)*8 + j][n_local = t*16 + (lane&15)]
// n_local -> gate = n_local>>3, jj = n_local&7, zcol = gate*512 + slice*8 + jj
__global__ void wconv_kernel(const float* __restrict__ Wf, const float* __restrict__ Uf,
                             const float* __restrict__ Wb, const float* __restrict__ Ub,
                             char* __restrict__ dst, int NC, int KX)
{
    int id = blockIdx.x * 256 + threadIdx.x;
    int j    = id & 7;
    int lane = (id >> 3) & 63;
    int t    = (id >> 9) & 1;
    int rest = id >> 10;            // (dir*64+slice)*NC + c
    int c    = rest % NC;
    int ds   = rest / NC;
    int slice = ds & 63;
    int dirr  = ds >> 6;
    int coll = t * 16 + (lane & 15);
    int k    = c * 32 + (lane >> 4) * 8 + j;
    int gate = coll >> 3, jj = coll & 7;
    int zcol = gate * 512 + slice * 8 + jj;
    const float* W = dirr ? Wb : Wf;
    const float* U = dirr ? Ub : Uf;
    float v = (k < KX) ? W[(size_t)k * NG + zcol] : U[(size_t)(k - KX) * NG + zcol];
    ((__bf16*)dst)[id] = (__bf16)v;
}

// ---------------- phase A: embedding gather + counter zero ----------------
__global__ void gather_x_kernel(const int* __restrict__ tokens, const float* __restrict__ emb,
                                char* __restrict__ ws)
{
    size_t id = (size_t)blockIdx.x * 256 + threadIdx.x;   // (t*64 + b)*256 + e
    int e = (int)(id & 255);
    int b = (int)((id >> 8) & 63);
    int t = (int)(id >> 14);
    int tok = tokens[b * TSEQ + t];
    ((__bf16*)(ws + OFF_X))[id] = (__bf16)emb[(size_t)tok * NE + e];
    if (id < 8) ((int*)(ws + OFF_CNT))[id] = 0;
}

// ---------------- phase B: persistent pipelined recurrence ----------------
__global__ __launch_bounds__(256, 1) void lstm_persist(
    char* __restrict__ ws,
    const float* __restrict__ b1f, const float* __restrict__ b2f,
    const float* __restrict__ b1b, const float* __restrict__ b2b)
{
    const int tid   = threadIdx.x;
    const int bid   = blockIdx.x;       // 256 wgs
    const int dir   = bid >> 7;
    const int layer = (bid >> 6) & 1;
    const int slice = bid & 63;

    const int NC = layer ? 32 : 24;     // total K chunks
    const int N0 = layer ? 16 : 8;      // part-1 chunks (x / h1-in)
    const int wbytes = NC * 2048;       // per-wg weight bytes (chunks*2 tiles*1KB)

    __shared__ char smem[65536];

    {
        const char* wsrc = ws + (layer ? OFF_W2 : OFF_W1) + (size_t)(dir * 64 + slice) * (size_t)wbytes;
        for (int i = tid * 16; i < wbytes; i += 256 * 16)
            *(uint4*)(smem + i) = *(const uint4*)(wsrc + i);
    }
    __syncthreads();

    __bf16* h1ring = (__bf16*)(ws + OFF_H1) + (size_t)dir * (4 * NB * NH);
    __bf16* h2ring = (__bf16*)(ws + OFF_H2) + (size_t)dir * (4 * NB * NH);
    const __bf16* Xall = (const __bf16*)(ws + OFF_X);
    __bf16* hfin = (__bf16*)(ws + OFF_HF) + (size_t)dir * (NB * NH);
    int* cnt = (int*)(ws + OFF_CNT);
    int* cL1 = &cnt[dir * 2 + 0];
    int* cL2 = &cnt[dir * 2 + 1];

    const int wv   = tid >> 6;
    const int lane = tid & 63;
    const int colc = lane & 15;
    const int q    = lane >> 4;
    const int m0   = wv * 16;
    const int mA   = m0 + colc;          // batch row for A operand
    const int jj   = colc & 7;
    const int hcol = slice * 8 + jj;     // hidden column this lane produces

    const float* bb = layer ? (dir ? b2b : b2f) : (dir ? b1b : b1f);
    const float bi  = bb[hcol];
    const float bf_ = bb[512 + hcol];
    const float bg  = bb[1024 + hcol];
    const float bo  = bb[1536 + hcol];

    float cst[4] = {0.f, 0.f, 0.f, 0.f};

    for (int s = 0; s < TSEQ; ++s) {
        // ---- wait for producers (and anti-overwrite slack) ----
        if (tid == 0) {
            if (layer == 0) {
                if (s > 0)
                    while (__hip_atomic_load(cL1, __ATOMIC_RELAXED, __HIP_MEMORY_SCOPE_AGENT) < 64 * s)
                        __builtin_amdgcn_s_sleep(2);
                if (s > 3)  // don't overwrite h1[s-4] until L2 finished step s-4
                    while (__hip_atomic_load(cL2, __ATOMIC_RELAXED, __HIP_MEMORY_SCOPE_AGENT) < 64 * (s - 3))
                        __builtin_amdgcn_s_sleep(2);
            } else {
                while (__hip_atomic_load(cL1, __ATOMIC_RELAXED, __HIP_MEMORY_SCOPE_AGENT) < 64 * (s + 1))
                    __builtin_amdgcn_s_sleep(2);
                if (s > 0)
                    while (__hip_atomic_load(cL2, __ATOMIC_RELAXED, __HIP_MEMORY_SCOPE_AGENT) < 64 * s)
                        __builtin_amdgcn_s_sleep(2);
            }
        }
        __syncthreads();
        __builtin_amdgcn_fence(__ATOMIC_ACQUIRE, "agent");

        // ---- A operand pointers ----
        const __bf16* pA0;
        const __bf16* pA1 = nullptr;
        if (layer == 0) {
            const int xs = dir ? (TSEQ - 1 - s) : s;
            pA0 = Xall + ((size_t)xs * NB + mA) * NE + q * 8;
            if (s > 0) pA1 = h1ring + (size_t)((s - 1) & 3) * (NB * NH) + (size_t)mA * NH + q * 8;
        } else {
            pA0 = h1ring + (size_t)(s & 3) * (NB * NH) + (size_t)mA * NH + q * 8;
            if (s > 0) pA1 = h2ring + (size_t)((s - 1) & 3) * (NB * NH) + (size_t)mA * NH + q * 8;
        }

        v4f acc0a = {0,0,0,0}, acc1a = {0,0,0,0};
        v4f acc0b = {0,0,0,0}, acc1b = {0,0,0,0};

        #pragma unroll
        for (int c = 0; c < N0; ++c) {
            v8bf a  = *(const v8bf*)(pA0 + c * 32);
            v8bf w0 = *(const v8bf*)(smem + (c * 2 + 0) * 1024 + lane * 16);
            v8bf w1 = *(const v8bf*)(smem + (c * 2 + 1) * 1024 + lane * 16);
            if (c & 1) { acc0b = MFMA16(a, w0, acc0b); acc1b = MFMA16(a, w1, acc1b); }
            else       { acc0a = MFMA16(a, w0, acc0a); acc1a = MFMA16(a, w1, acc1a); }
        }
        if (pA1) {
            #pragma unroll
            for (int c = 0; c < 16; ++c) {
                v8bf a  = *(const v8bf*)(pA1 + c * 32);
                v8bf w0 = *(const v8bf*)(smem + ((N0 + c) * 2 + 0) * 1024 + lane * 16);
                v8bf w1 = *(const v8bf*)(smem + ((N0 + c) * 2 + 1) * 1024 + lane * 16);
                if (c & 1) { acc0b = MFMA16(a, w0, acc0b); acc1b = MFMA16(a, w1, acc1b); }
                else       { acc0a = MFMA16(a, w0, acc0a); acc1a = MFMA16(a, w1, acc1a); }
            }
        }
        v4f z0 = acc0a + acc0b;   // tile0: gates i (cols 0-7) / f (cols 8-15)
        v4f z1 = acc1a + acc1b;   // tile1: gates g / o

        // ---- gate nonlinearity; lanes col and col^8 exchange (i,g)<->(f,o) ----
        float hv[4];
        #pragma unroll
        for (int r = 0; r < 4; ++r) {
            float p0 = __shfl_xor(z0[r], 8, 64);
            float p1 = __shfl_xor(z1[r], 8, 64);
            float zi, zf, zg, zo;
            if (colc < 8) { zi = z0[r]; zf = p0;    zg = z1[r]; zo = p1;    }
            else          { zi = p0;    zf = z0[r]; zg = p1;    zo = z1[r]; }
            zi += bi; zf += bf_; zg += bg; zo += bo;
            float gi = 1.f / (1.f + __expf(-zi));
            float gf = 1.f / (1.f + __expf(-zf));
            float gg = 1.f - 2.f / (1.f + __expf(2.f * zg));   // tanh
            float go = 1.f / (1.f + __expf(-zo));
            float cn = gf * cst[r] + gi * gg;
            cst[r] = cn;
            float th = 1.f - 2.f / (1.f + __expf(2.f * cn));   // tanh
            hv[r] = go * th;
        }

        // ---- store h slice (lanes col<8 hold the canonical copy) ----
        __bf16* hdst = (layer ? h2ring : h1ring) + (size_t)(s & 3) * (NB * NH);
        if (colc < 8) {
            #pragma unroll
            for (int r = 0; r < 4; ++r) {
                int row = m0 + q * 4 + r;
                hdst[(size_t)row * NH + hcol] = (__bf16)hv[r];
                if (layer == 1 && s == TSEQ - 1)
                    hfin[(size_t)row * NH + hcol] = (__bf16)hv[r];
            }
        }

        __builtin_amdgcn_fence(__ATOMIC_RELEASE, "agent");
        __syncthreads();
        if (tid == 0)
            __hip_atomic_fetch_add(layer ? cL2 : cL1, 1, __ATOMIC_RELAXED, __HIP_MEMORY_SCOPE_AGENT);
    }
}

// ---------------- phase C: dense head [64,1024]@[1024,5]+bd ----------------
__global__ void head_kernel(const char* __restrict__ ws, const float* __restrict__ Wd,
                            const float* __restrict__ bd, float* __restrict__ out)
{
    int b = blockIdx.x;
    int lane = threadIdx.x;   // 64
    const __bf16* hfF = (const __bf16*)(ws + OFF_HF) + (size_t)b * NH;
    const __bf16* hfB = (const __bf16*)(ws + OFF_HF) + (size_t)(NB * NH) + (size_t)b * NH;
    #pragma unroll
    for (int o = 0; o < 5; ++o) {
        float sum = 0.f;
        for (int k = lane; k < 2 * NH; k += 64) {
            float fv = (k < NH) ? (float)hfF[k] : (float)hfB[k - NH];
            sum += fv * Wd[(size_t)k * 5 + o];
        }
        #pragma unroll
        for (int off = 32; off > 0; off >>= 1) sum += __shfl_down(sum, off, 64);
        if (lane == 0) out[b * 5 + o] = sum + bd[o];
    }
}

// ---------------- launch ----------------
extern "C" void kernel_launch(void* const* d_in, const int* in_sizes, int n_in,
                              void* d_out, int out_size, void* d_ws, size_t ws_size,
                              hipStream_t stream)
{
    const int*   tokens = (const int*)  d_in[0];
    const float* emb    = (const float*)d_in[1];
    const float* W1f    = (const float*)d_in[2];
    const float* U1f    = (const float*)d_in[3];
    const float* b1f    = (const float*)d_in[4];
    const float* W2f    = (const float*)d_in[5];
    const float* U2f    = (const float*)d_in[6];
    const float* b2f    = (const float*)d_in[7];
    const float* W1b    = (const float*)d_in[8];
    const float* U1b    = (const float*)d_in[9];
    const float* b1b    = (const float*)d_in[10];
    const float* W2b    = (const float*)d_in[11];
    const float* U2b    = (const float*)d_in[12];
    const float* b2b    = (const float*)d_in[13];
    const float* Wd     = (const float*)d_in[14];
    const float* bd     = (const float*)d_in[15];
    char* ws = (char*)d_ws;

    // phase A: weight swizzle (L1: NC=24, KX=256; L2: NC=32, KX=512)
    wconv_kernel<<<12288, 256, 0, stream>>>(W1f, U1f, W1b, U1b, ws + OFF_W1, 24, 256);
    wconv_kernel<<<16384, 256, 0, stream>>>(W2f, U2f, W2b, U2b, ws + OFF_W2, 32, 512);
    // phase A: embedding gather + counter init
    gather_x_kernel<<<32768, 256, 0, stream>>>(tokens, emb, ws);
    // phase B: persistent recurrence (256 wgs, all co-resident on 256 CUs)
    lstm_persist<<<256, 256, 0, stream>>>(ws, b1f, b2f, b1b, b2b);
    // phase C: head
    head_kernel<<<NB, 64, 0, stream>>>(ws, Wd, bd, (float*)d_out);
}

// Round 2
// 6874.744 us; speedup vs baseline: 3.0213x; 3.0213x over previous
//
#include <hip/hip_runtime.h>
#include <hip/hip_bf16.h>

// ---------------- problem constants ----------------
#define TSEQ 512
#define NB   64
#define NE   256
#define NH   512
#define NG   2048   // 4*NH

// ---------------- workspace layout (bytes) ----------------
static const size_t OFF_W1  = 0;          // 6,291,456
static const size_t OFF_W2  = 6291456;    // 8,388,608
static const size_t OFF_X   = 14680064;   // 16,777,216
static const size_t OFF_H1  = 31457280;   // 524,288
static const size_t OFF_H2  = 31981568;   // 524,288
static const size_t OFF_HF  = 32505856;   // 131,072
static const size_t OFF_CNT = 32636928;   // 512 B (counters 128B-strided)

typedef __bf16 v8bf __attribute__((ext_vector_type(8)));
typedef float  v4f  __attribute__((ext_vector_type(4)));

#define MFMA16(a_, b_, c_) __builtin_amdgcn_mfma_f32_16x16x32_bf16((a_), (b_), (c_), 0, 0, 0)

// Coherent 16B h-fragment load: two 8B relaxed agent-scope atomic loads.
// These emit per-access cache-bypass (sc0 sc1) — always read the coherent
// point; no buffer_inv needed anywhere.
static __device__ __forceinline__ v8bf load_h8(const __bf16* p) {
    unsigned long long lo = __hip_atomic_load((unsigned long long*)p,     __ATOMIC_RELAXED, __HIP_MEMORY_SCOPE_AGENT);
    unsigned long long hi = __hip_atomic_load((unsigned long long*)p + 1, __ATOMIC_RELAXED, __HIP_MEMORY_SCOPE_AGENT);
    union { unsigned long long q[2]; v8bf v; } u;
    u.q[0] = lo; u.q[1] = hi;
    return u.v;
}

static __device__ __forceinline__ unsigned short bf16_bits(float f) {
    __bf16 b = (__bf16)f;
    return __builtin_bit_cast(unsigned short, b);
}

// ---------------- phase A: weight convert to fragment-linear bf16 ----------------
__global__ void wconv_kernel(const float* __restrict__ Wf, const float* __restrict__ Uf,
                             const float* __restrict__ Wb, const float* __restrict__ Ub,
                             char* __restrict__ dst, int NC, int KX)
{
    int id = blockIdx.x * 256 + threadIdx.x;
    int j    = id & 7;
    int lane = (id >> 3) & 63;
    int t    = (id >> 9) & 1;
    int rest = id >> 10;            // (dir*64+slice)*NC + c
    int c    = rest % NC;
    int ds   = rest / NC;
    int slice = ds & 63;
    int dirr  = ds >> 6;
    int coll = t * 16 + (lane & 15);
    int k    = c * 32 + (lane >> 4) * 8 + j;
    int gate = coll >> 3, jj = coll & 7;
    int zcol = gate * 512 + slice * 8 + jj;
    const float* W = dirr ? Wb : Wf;
    const float* U = dirr ? Ub : Uf;
    float v = (k < KX) ? W[(size_t)k * NG + zcol] : U[(size_t)(k - KX) * NG + zcol];
    ((__bf16*)dst)[id] = (__bf16)v;
}

// ---------------- phase A: embedding gather + counter zero ----------------
__global__ void gather_x_kernel(const int* __restrict__ tokens, const float* __restrict__ emb,
                                char* __restrict__ ws)
{
    size_t id = (size_t)blockIdx.x * 256 + threadIdx.x;   // (t*64 + b)*256 + e
    int e = (int)(id & 255);
    int b = (int)((id >> 8) & 63);
    int t = (int)(id >> 14);
    int tok = tokens[b * TSEQ + t];
    ((__bf16*)(ws + OFF_X))[id] = (__bf16)emb[(size_t)tok * NE + e];
    if (id < 128) ((int*)(ws + OFF_CNT))[id] = 0;
}

// ---------------- phase B: persistent pipelined recurrence ----------------
// LAYER-templated step loop so A-fragment arrays are compile-time sized.
template<int LAYER>
static __device__ void run_layer(
    char* __restrict__ ws, const char* __restrict__ smem,
    int dir, int slice, int tid,
    const float* __restrict__ bb)
{
    const int N0 = LAYER ? 16 : 8;       // part-1 chunks (x or h1-in)

    __bf16* h1ring = (__bf16*)(ws + OFF_H1) + (size_t)dir * (4 * NB * NH);
    __bf16* h2ring = (__bf16*)(ws + OFF_H2) + (size_t)dir * (4 * NB * NH);
    const __bf16* Xall = (const __bf16*)(ws + OFF_X);
    __bf16* hfin = (__bf16*)(ws + OFF_HF) + (size_t)dir * (NB * NH);
    int* cnt = (int*)(ws + OFF_CNT);
    int* cL1 = cnt + dir * 64 + 0;       // 128B-separated counter lines
    int* cL2 = cnt + dir * 64 + 32;

    const int wv   = tid >> 6;
    const int lane = tid & 63;
    const int colc = lane & 15;
    const int q    = lane >> 4;
    const int m0   = wv * 16;
    const int mA   = m0 + colc;
    const int jj   = colc & 7;
    const int hcol = slice * 8 + jj;

    const float bi  = bb[hcol];
    const float bf_ = bb[512 + hcol];
    const float bg  = bb[1024 + hcol];
    const float bo  = bb[1536 + hcol];

    float cst[4] = {0.f, 0.f, 0.f, 0.f};

    for (int s = 0; s < TSEQ; ++s) {
        // ---- wait for producers (relaxed agent polls; no fences) ----
        if (tid == 0) {
            if (LAYER == 0) {
                if (s > 0)
                    while (__hip_atomic_load(cL1, __ATOMIC_RELAXED, __HIP_MEMORY_SCOPE_AGENT) < 64 * s)
                        __builtin_amdgcn_s_sleep(2);
                if (s > 3)
                    while (__hip_atomic_load(cL2, __ATOMIC_RELAXED, __HIP_MEMORY_SCOPE_AGENT) < 64 * (s - 3))
                        __builtin_amdgcn_s_sleep(2);
            } else {
                while (__hip_atomic_load(cL1, __ATOMIC_RELAXED, __HIP_MEMORY_SCOPE_AGENT) < 64 * (s + 1))
                    __builtin_amdgcn_s_sleep(2);
                if (s > 0)
                    while (__hip_atomic_load(cL2, __ATOMIC_RELAXED, __HIP_MEMORY_SCOPE_AGENT) < 64 * s)
                        __builtin_amdgcn_s_sleep(2);
            }
        }
        __syncthreads();

        v4f acc0a = {0,0,0,0}, acc1a = {0,0,0,0};
        v4f acc0b = {0,0,0,0}, acc1b = {0,0,0,0};

        if (LAYER == 0) {
            const int xs = dir ? (TSEQ - 1 - s) : s;
            const __bf16* pA0 = Xall + ((size_t)xs * NB + mA) * NE + q * 8;
            // issue ALL coherent h loads up front (hand-hoisted: compiler
            // won't reorder relaxed atomics past each other)
            v8bf ah[16];
            if (s > 0) {
                const __bf16* pA1 = h1ring + (size_t)((s - 1) & 3) * (NB * NH) + (size_t)mA * NH + q * 8;
                #pragma unroll
                for (int c = 0; c < 16; ++c) ah[c] = load_h8(pA1 + c * 32);
            }
            // X part (normal cached loads) overlaps the h-load flight time
            #pragma unroll
            for (int c = 0; c < 8; ++c) {
                v8bf a  = *(const v8bf*)(pA0 + c * 32);
                v8bf w0 = *(const v8bf*)(smem + (c * 2 + 0) * 1024 + lane * 16);
                v8bf w1 = *(const v8bf*)(smem + (c * 2 + 1) * 1024 + lane * 16);
                if (c & 1) { acc0b = MFMA16(a, w0, acc0b); acc1b = MFMA16(a, w1, acc1b); }
                else       { acc0a = MFMA16(a, w0, acc0a); acc1a = MFMA16(a, w1, acc1a); }
            }
            if (s > 0) {
                #pragma unroll
                for (int c = 0; c < 16; ++c) {
                    v8bf w0 = *(const v8bf*)(smem + ((N0 + c) * 2 + 0) * 1024 + lane * 16);
                    v8bf w1 = *(const v8bf*)(smem + ((N0 + c) * 2 + 1) * 1024 + lane * 16);
                    if (c & 1) { acc0b = MFMA16(ah[c], w0, acc0b); acc1b = MFMA16(ah[c], w1, acc1b); }
                    else       { acc0a = MFMA16(ah[c], w0, acc0a); acc1a = MFMA16(ah[c], w1, acc1a); }
                }
            }
        } else {
            const __bf16* pA0 = h1ring + (size_t)(s & 3) * (NB * NH) + (size_t)mA * NH + q * 8;
            v8bf a0[16], a1[16];
            #pragma unroll
            for (int c = 0; c < 16; ++c) a0[c] = load_h8(pA0 + c * 32);
            if (s > 0) {
                const __bf16* pA1 = h2ring + (size_t)((s - 1) & 3) * (NB * NH) + (size_t)mA * NH + q * 8;
                #pragma unroll
                for (int c = 0; c < 16; ++c) a1[c] = load_h8(pA1 + c * 32);
            }
            #pragma unroll
            for (int c = 0; c < 16; ++c) {
                v8bf w0 = *(const v8bf*)(smem + (c * 2 + 0) * 1024 + lane * 16);
                v8bf w1 = *(const v8bf*)(smem + (c * 2 + 1) * 1024 + lane * 16);
                if (c & 1) { acc0b = MFMA16(a0[c], w0, acc0b); acc1b = MFMA16(a0[c], w1, acc1b); }
                else       { acc0a = MFMA16(a0[c], w0, acc0a); acc1a = MFMA16(a0[c], w1, acc1a); }
            }
            if (s > 0) {
                #pragma unroll
                for (int c = 0; c < 16; ++c) {
                    v8bf w0 = *(const v8bf*)(smem + ((16 + c) * 2 + 0) * 1024 + lane * 16);
                    v8bf w1 = *(const v8bf*)(smem + ((16 + c) * 2 + 1) * 1024 + lane * 16);
                    if (c & 1) { acc0b = MFMA16(a1[c], w0, acc0b); acc1b = MFMA16(a1[c], w1, acc1b); }
                    else       { acc0a = MFMA16(a1[c], w0, acc0a); acc1a = MFMA16(a1[c], w1, acc1a); }
                }
            }
        }

        v4f z0 = acc0a + acc0b;   // gates i (cols 0-7) / f (cols 8-15)
        v4f z1 = acc1a + acc1b;   // gates g / o

        // ---- gate nonlinearity; lanes col and col^8 exchange ----
        float hv[4];
        #pragma unroll
        for (int r = 0; r < 4; ++r) {
            float p0 = __shfl_xor(z0[r], 8, 64);
            float p1 = __shfl_xor(z1[r], 8, 64);
            float zi, zf, zg, zo;
            if (colc < 8) { zi = z0[r]; zf = p0;    zg = z1[r]; zo = p1;    }
            else          { zi = p0;    zf = z0[r]; zg = p1;    zo = z1[r]; }
            zi += bi; zf += bf_; zg += bg; zo += bo;
            float gi = 1.f / (1.f + __expf(-zi));
            float gf = 1.f / (1.f + __expf(-zf));
            float gg = 1.f - 2.f / (1.f + __expf(2.f * zg));   // tanh
            float go = 1.f / (1.f + __expf(-zo));
            float cn = gf * cst[r] + gi * gg;
            cst[r] = cn;
            float th = 1.f - 2.f / (1.f + __expf(2.f * cn));   // tanh
            hv[r] = go * th;
        }

        // ---- write-through h stores (pack col pairs -> one dword) ----
        __bf16* hdst = (LAYER ? h2ring : h1ring) + (size_t)(s & 3) * (NB * NH);
        if (colc < 8) {
            #pragma unroll
            for (int r = 0; r < 4; ++r) {
                float pv = __shfl_xor(hv[r], 1, 64);
                unsigned short m = bf16_bits(hv[r]);
                unsigned short p = bf16_bits(pv);
                int row = m0 + q * 4 + r;
                if (!(colc & 1)) {
                    unsigned int val = (unsigned int)m | ((unsigned int)p << 16);
                    __hip_atomic_store((unsigned int*)&hdst[(size_t)row * NH + hcol], val,
                                       __ATOMIC_RELAXED, __HIP_MEMORY_SCOPE_AGENT);
                }
                if (LAYER == 1 && s == TSEQ - 1)
                    hfin[(size_t)row * NH + hcol] = (__bf16)hv[r];   // normal store; kernel boundary publishes
            }
        }

        // drain my write-through stores, then one signal per wg
        __builtin_amdgcn_s_waitcnt(0);
        __syncthreads();
        if (tid == 0)
            __hip_atomic_fetch_add(LAYER ? cL2 : cL1, 1, __ATOMIC_RELAXED, __HIP_MEMORY_SCOPE_AGENT);
    }
}

__global__ __launch_bounds__(256, 1) void lstm_persist(
    char* __restrict__ ws,
    const float* __restrict__ b1f, const float* __restrict__ b2f,
    const float* __restrict__ b1b, const float* __restrict__ b2b)
{
    const int tid   = threadIdx.x;
    const int bid   = blockIdx.x;       // 256 wgs
    const int dir   = bid >> 7;
    const int layer = (bid >> 6) & 1;
    const int slice = bid & 63;

    const int NC = layer ? 32 : 24;
    const int wbytes = NC * 2048;

    __shared__ char smem[65536];
    {
        const char* wsrc = ws + (layer ? OFF_W2 : OFF_W1) + (size_t)(dir * 64 + slice) * (size_t)wbytes;
        for (int i = tid * 16; i < wbytes; i += 256 * 16)
            *(uint4*)(smem + i) = *(const uint4*)(wsrc + i);
    }
    __syncthreads();

    const float* bb = layer ? (dir ? b2b : b2f) : (dir ? b1b : b1f);
    if (layer == 0) run_layer<0>(ws, smem, dir, slice, tid, bb);
    else            run_layer<1>(ws, smem, dir, slice, tid, bb);
}

// ---------------- phase C: dense head [64,1024]@[1024,5]+bd ----------------
__global__ void head_kernel(const char* __restrict__ ws, const float* __restrict__ Wd,
                            const float* __restrict__ bd, float* __restrict__ out)
{
    int b = blockIdx.x;
    int lane = threadIdx.x;   // 64
    const __bf16* hfF = (const __bf16*)(ws + OFF_HF) + (size_t)b * NH;
    const __bf16* hfB = (const __bf16*)(ws + OFF_HF) + (size_t)(NB * NH) + (size_t)b * NH;
    #pragma unroll
    for (int o = 0; o < 5; ++o) {
        float sum = 0.f;
        for (int k = lane; k < 2 * NH; k += 64) {
            float fv = (k < NH) ? (float)hfF[k] : (float)hfB[k - NH];
            sum += fv * Wd[(size_t)k * 5 + o];
        }
        #pragma unroll
        for (int off = 32; off > 0; off >>= 1) sum += __shfl_down(sum, off, 64);
        if (lane == 0) out[b * 5 + o] = sum + bd[o];
    }
}

// ---------------- launch ----------------
extern "C" void kernel_launch(void* const* d_in, const int* in_sizes, int n_in,
                              void* d_out, int out_size, void* d_ws, size_t ws_size,
                              hipStream_t stream)
{
    const int*   tokens = (const int*)  d_in[0];
    const float* emb    = (const float*)d_in[1];
    const float* W1f    = (const float*)d_in[2];
    const float* U1f    = (const float*)d_in[3];
    const float* b1f    = (const float*)d_in[4];
    const float* W2f    = (const float*)d_in[5];
    const float* U2f    = (const float*)d_in[6];
    const float* b2f    = (const float*)d_in[7];
    const float* W1b    = (const float*)d_in[8];
    const float* U1b    = (const float*)d_in[9];
    const float* b1b    = (const float*)d_in[10];
    const float* W2b    = (const float*)d_in[11];
    const float* U2b    = (const float*)d_in[12];
    const float* b2b    = (const float*)d_in[13];
    const float* Wd     = (const float*)d_in[14];
    const float* bd     = (const float*)d_in[15];
    char* ws = (char*)d_ws;

    wconv_kernel<<<12288, 256, 0, stream>>>(W1f, U1f, W1b, U1b, ws + OFF_W1, 24, 256);
    wconv_kernel<<<16384, 256, 0, stream>>>(W2f, U2f, W2b, U2b, ws + OFF_W2, 32, 512);
    gather_x_kernel<<<32768, 256, 0, stream>>>(tokens, emb, ws);
    lstm_persist<<<256, 256, 0, stream>>>(ws, b1f, b2f, b1b, b2b);
    head_kernel<<<NB, 64, 0, stream>>>(ws, Wd, bd, (float*)d_out);
}

// Round 3
// 5338.075 us; speedup vs baseline: 3.8911x; 1.2879x over previous
//
#include <hip/hip_runtime.h>
#include <hip/hip_bf16.h>

// ---------------- problem constants ----------------
#define TSEQ 512
#define NB   64
#define NE   256
#define NH   512
#define NG   2048   // 4*NH

// ---------------- workspace layout (bytes) ----------------
static const size_t OFF_W1  = 0;          // 6,291,456
static const size_t OFF_W2  = 6291456;    // 8,388,608
static const size_t OFF_X   = 14680064;   // 16,777,216
static const size_t OFF_H1  = 31457280;   // 524,288
static const size_t OFF_H2  = 31981568;   // 524,288
static const size_t OFF_HF  = 32505856;   // 131,072
static const size_t OFF_CNT = 32636928;   // flags: 4 domains * 64 slices * 128B = 32 KB

typedef __bf16 v8bf __attribute__((ext_vector_type(8)));
typedef float  v4f  __attribute__((ext_vector_type(4)));

#define MFMA16(a_, b_, c_) __builtin_amdgcn_mfma_f32_16x16x32_bf16((a_), (b_), (c_), 0, 0, 0)

// Coherent 16B h-fragment load: two 8B relaxed agent-scope atomic loads
// (per-access cache-bypass; always read the coherent point).
static __device__ __forceinline__ v8bf load_h8(const __bf16* p) {
    unsigned long long lo = __hip_atomic_load((unsigned long long*)p,     __ATOMIC_RELAXED, __HIP_MEMORY_SCOPE_AGENT);
    unsigned long long hi = __hip_atomic_load((unsigned long long*)p + 1, __ATOMIC_RELAXED, __HIP_MEMORY_SCOPE_AGENT);
    union { unsigned long long q[2]; v8bf v; } u;
    u.q[0] = lo; u.q[1] = hi;
    return u.v;
}

static __device__ __forceinline__ unsigned short bf16_bits(float f) {
    __bf16 b = (__bf16)f;
    return __builtin_bit_cast(unsigned short, b);
}

// ---------------- phase A: weight convert to fragment-linear bf16 ----------------
__global__ void wconv_kernel(const float* __restrict__ Wf, const float* __restrict__ Uf,
                             const float* __restrict__ Wb, const float* __restrict__ Ub,
                             char* __restrict__ dst, int NC, int KX)
{
    int id = blockIdx.x * 256 + threadIdx.x;
    int j    = id & 7;
    int lane = (id >> 3) & 63;
    int t    = (id >> 9) & 1;
    int rest = id >> 10;            // (dir*64+slice)*NC + c
    int c    = rest % NC;
    int ds   = rest / NC;
    int slice = ds & 63;
    int dirr  = ds >> 6;
    int coll = t * 16 + (lane & 15);
    int k    = c * 32 + (lane >> 4) * 8 + j;
    int gate = coll >> 3, jj = coll & 7;
    int zcol = gate * 512 + slice * 8 + jj;
    const float* W = dirr ? Wb : Wf;
    const float* U = dirr ? Ub : Uf;
    float v = (k < KX) ? W[(size_t)k * NG + zcol] : U[(size_t)(k - KX) * NG + zcol];
    ((__bf16*)dst)[id] = (__bf16)v;
}

// ---------------- phase A: embedding gather + flag zero ----------------
__global__ void gather_x_kernel(const int* __restrict__ tokens, const float* __restrict__ emb,
                                char* __restrict__ ws)
{
    size_t id = (size_t)blockIdx.x * 256 + threadIdx.x;   // (t*64 + b)*256 + e
    int e = (int)(id & 255);
    int b = (int)((id >> 8) & 63);
    int t = (int)(id >> 14);
    int tok = tokens[b * TSEQ + t];
    ((__bf16*)(ws + OFF_X))[id] = (__bf16)emb[(size_t)tok * NE + e];
    if (id < 8192) ((int*)(ws + OFF_CNT))[id] = 0;        // 4 domains * 64 * 32 ints
}

// ---------------- phase B: persistent pipelined recurrence ----------------
// Weights are VGPR-resident (no LDS). Sync is per-producer flags polled
// lane-parallel by every wave. h traffic is coherent (cache-bypass) atomics.
template<int LAYER>
__device__ void run_layer(char* __restrict__ ws, int dir, int slice, int tid,
                          const float* __restrict__ bb)
{
    const int NC = LAYER ? 32 : 24;      // K chunks (K = NC*32)

    const int lane = tid & 63;
    const int wv   = tid >> 6;
    const int colc = lane & 15;
    const int q    = lane >> 4;
    const int m0   = wv * 16;
    const int mA   = m0 + colc;
    const int jj   = colc & 7;
    const int hcol = slice * 8 + jj;

    // ---- load my weight slice into registers (fragment-linear layout) ----
    v8bf w[2 * (LAYER ? 32 : 24)];
    {
        const char* wsrc = ws + (LAYER ? OFF_W2 : OFF_W1)
                         + (size_t)(dir * 64 + slice) * (size_t)(NC * 2048);
        #pragma unroll
        for (int i = 0; i < 2 * NC; ++i)
            w[i] = *(const v8bf*)(wsrc + ((size_t)i * 64 + lane) * 16);
    }

    __bf16* h1ring = (__bf16*)(ws + OFF_H1) + (size_t)dir * (4 * NB * NH);
    __bf16* h2ring = (__bf16*)(ws + OFF_H2) + (size_t)dir * (4 * NB * NH);
    const __bf16* Xall = (const __bf16*)(ws + OFF_X);
    __bf16* hfin = (__bf16*)(ws + OFF_HF) + (size_t)dir * (NB * NH);

    int* flags = (int*)(ws + OFF_CNT);
    int* f1 = flags + (dir * 2 + 0) * 2048;   // L1 flags, 32-int (128B) stride
    int* f2 = flags + (dir * 2 + 1) * 2048;   // L2 flags
    int* fown = (LAYER ? f2 : f1) + slice * 32;
    int* fp1 = f1 + lane * 32;                // this lane's poll targets
    int* fp2 = f2 + lane * 32;

    const float bi  = bb[hcol];
    const float bf_ = bb[512 + hcol];
    const float bg  = bb[1024 + hcol];
    const float bo  = bb[1536 + hcol];

    float cst[4] = {0.f, 0.f, 0.f, 0.f};

    for (int s = 0; s < TSEQ; ++s) {
        v4f acc0a = {0,0,0,0}, acc1a = {0,0,0,0};
        v4f acc0b = {0,0,0,0}, acc1b = {0,0,0,0};

        // ---- L1: x-part has no step dependency — compute BEFORE the poll ----
        if (LAYER == 0) {
            const int xs = dir ? (TSEQ - 1 - s) : s;
            const __bf16* pA0 = Xall + ((size_t)xs * NB + mA) * NE + q * 8;
            #pragma unroll
            for (int c = 0; c < 8; ++c) {
                v8bf a = *(const v8bf*)(pA0 + c * 32);
                if (c & 1) { acc0b = MFMA16(a, w[c*2], acc0b); acc1b = MFMA16(a, w[c*2+1], acc1b); }
                else       { acc0a = MFMA16(a, w[c*2], acc0a); acc1a = MFMA16(a, w[c*2+1], acc1a); }
            }
        }

        // ---- lane-parallel flag poll (every wave polls independently) ----
        // L1 step s: all L1 done s-1 (f1>=s), all L2 done s-4 (f2>=s-3, ring guard)
        // L2 step s: all L1 done s   (f1>=s+1), all L2 done s-1 (f2>=s)
        {
            const int t1 = (LAYER == 0) ? s : s + 1;
            const int t2 = (LAYER == 0) ? s - 3 : s;
            if (t1 > 0) {
                while (true) {
                    int v1 = __hip_atomic_load(fp1, __ATOMIC_RELAXED, __HIP_MEMORY_SCOPE_AGENT);
                    int v2 = __hip_atomic_load(fp2, __ATOMIC_RELAXED, __HIP_MEMORY_SCOPE_AGENT);
                    if (__all((v1 >= t1) && (v2 >= t2))) break;
                    __builtin_amdgcn_s_sleep(1);
                }
            }
        }

        // ---- h-dependent MFMA work ----
        if (LAYER == 0) {
            if (s > 0) {
                const __bf16* pA1 = h1ring + (size_t)((s - 1) & 3) * (NB * NH) + (size_t)mA * NH + q * 8;
                v8bf ah[16];
                #pragma unroll
                for (int c = 0; c < 16; ++c) ah[c] = load_h8(pA1 + c * 32);
                __builtin_amdgcn_sched_barrier(0);   // all loads issue before first MFMA wait
                #pragma unroll
                for (int c = 0; c < 16; ++c) {
                    if (c & 1) { acc0b = MFMA16(ah[c], w[(8+c)*2], acc0b); acc1b = MFMA16(ah[c], w[(8+c)*2+1], acc1b); }
                    else       { acc0a = MFMA16(ah[c], w[(8+c)*2], acc0a); acc1a = MFMA16(ah[c], w[(8+c)*2+1], acc1a); }
                }
            }
        } else {
            const __bf16* pA0 = h1ring + (size_t)(s & 3) * (NB * NH) + (size_t)mA * NH + q * 8;
            v8bf a0[16], a1[16];
            #pragma unroll
            for (int c = 0; c < 16; ++c) a0[c] = load_h8(pA0 + c * 32);
            if (s > 0) {
                const __bf16* pA1 = h2ring + (size_t)((s - 1) & 3) * (NB * NH) + (size_t)mA * NH + q * 8;
                #pragma unroll
                for (int c = 0; c < 16; ++c) a1[c] = load_h8(pA1 + c * 32);
            }
            __builtin_amdgcn_sched_barrier(0);
            #pragma unroll
            for (int c = 0; c < 16; ++c) {
                if (c & 1) { acc0b = MFMA16(a0[c], w[c*2], acc0b); acc1b = MFMA16(a0[c], w[c*2+1], acc1b); }
                else       { acc0a = MFMA16(a0[c], w[c*2], acc0a); acc1a = MFMA16(a0[c], w[c*2+1], acc1a); }
            }
            if (s > 0) {
                #pragma unroll
                for (int c = 0; c < 16; ++c) {
                    if (c & 1) { acc0b = MFMA16(a1[c], w[(16+c)*2], acc0b); acc1b = MFMA16(a1[c], w[(16+c)*2+1], acc1b); }
                    else       { acc0a = MFMA16(a1[c], w[(16+c)*2], acc0a); acc1a = MFMA16(a1[c], w[(16+c)*2+1], acc1a); }
                }
            }
        }

        v4f z0 = acc0a + acc0b;   // gates i (cols 0-7) / f (cols 8-15)
        v4f z1 = acc1a + acc1b;   // gates g / o

        // ---- gate nonlinearity; lanes col and col^8 exchange ----
        float hv[4];
        #pragma unroll
        for (int r = 0; r < 4; ++r) {
            float p0 = __shfl_xor(z0[r], 8, 64);
            float p1 = __shfl_xor(z1[r], 8, 64);
            float zi, zf, zg, zo;
            if (colc < 8) { zi = z0[r]; zf = p0;    zg = z1[r]; zo = p1;    }
            else          { zi = p0;    zf = z0[r]; zg = p1;    zo = z1[r]; }
            zi += bi; zf += bf_; zg += bg; zo += bo;
            float gi = 1.f / (1.f + __expf(-zi));
            float gf = 1.f / (1.f + __expf(-zf));
            float gg = 1.f - 2.f / (1.f + __expf(2.f * zg));   // tanh
            float go = 1.f / (1.f + __expf(-zo));
            float cn = gf * cst[r] + gi * gg;
            cst[r] = cn;
            float th = 1.f - 2.f / (1.f + __expf(2.f * cn));   // tanh
            hv[r] = go * th;
        }

        // ---- write-through h stores (pack col pairs -> one dword) ----
        __bf16* hdst = (LAYER ? h2ring : h1ring) + (size_t)(s & 3) * (NB * NH);
        if (colc < 8) {
            #pragma unroll
            for (int r = 0; r < 4; ++r) {
                float pv = __shfl_xor(hv[r], 1, 64);
                unsigned short m = bf16_bits(hv[r]);
                unsigned short p = bf16_bits(pv);
                int row = m0 + q * 4 + r;
                if (!(colc & 1)) {
                    unsigned int val = (unsigned int)m | ((unsigned int)p << 16);
                    __hip_atomic_store((unsigned int*)&hdst[(size_t)row * NH + hcol], val,
                                       __ATOMIC_RELAXED, __HIP_MEMORY_SCOPE_AGENT);
                }
                if (LAYER == 1 && s == TSEQ - 1)
                    hfin[(size_t)row * NH + hcol] = (__bf16)hv[r];   // kernel boundary publishes
            }
        }

        // drain this wave's stores, converge the wg, publish one flag
        __builtin_amdgcn_s_waitcnt(0);
        __syncthreads();
        if (tid == 0)
            __hip_atomic_store(fown, s + 1, __ATOMIC_RELAXED, __HIP_MEMORY_SCOPE_AGENT);
    }
}

__global__ __launch_bounds__(256, 1) void lstm_persist(
    char* __restrict__ ws,
    const float* __restrict__ b1f, const float* __restrict__ b2f,
    const float* __restrict__ b1b, const float* __restrict__ b2b)
{
    const int tid   = threadIdx.x;
    const int bid   = blockIdx.x;       // 256 wgs
    const int dir   = bid >> 7;
    const int layer = (bid >> 6) & 1;
    const int slice = bid & 63;

    const float* bb = layer ? (dir ? b2b : b2f) : (dir ? b1b : b1f);
    if (layer == 0) run_layer<0>(ws, dir, slice, tid, bb);
    else            run_layer<1>(ws, dir, slice, tid, bb);
}

// ---------------- phase C: dense head [64,1024]@[1024,5]+bd ----------------
__global__ void head_kernel(const char* __restrict__ ws, const float* __restrict__ Wd,
                            const float* __restrict__ bd, float* __restrict__ out)
{
    int b = blockIdx.x;
    int lane = threadIdx.x;   // 64
    const __bf16* hfF = (const __bf16*)(ws + OFF_HF) + (size_t)b * NH;
    const __bf16* hfB = (const __bf16*)(ws + OFF_HF) + (size_t)(NB * NH) + (size_t)b * NH;
    #pragma unroll
    for (int o = 0; o < 5; ++o) {
        float sum = 0.f;
        for (int k = lane; k < 2 * NH; k += 64) {
            float fv = (k < NH) ? (float)hfF[k] : (float)hfB[k - NH];
            sum += fv * Wd[(size_t)k * 5 + o];
        }
        #pragma unroll
        for (int off = 32; off > 0; off >>= 1) sum += __shfl_down(sum, off, 64);
        if (lane == 0) out[b * 5 + o] = sum + bd[o];
    }
}

// ---------------- launch ----------------
extern "C" void kernel_launch(void* const* d_in, const int* in_sizes, int n_in,
                              void* d_out, int out_size, void* d_ws, size_t ws_size,
                              hipStream_t stream)
{
    const int*   tokens = (const int*)  d_in[0];
    const float* emb    = (const float*)d_in[1];
    const float* W1f    = (const float*)d_in[2];
    const float* U1f    = (const float*)d_in[3];
    const float* b1f    = (const float*)d_in[4];
    const float* W2f    = (const float*)d_in[5];
    const float* U2f    = (const float*)d_in[6];
    const float* b2f    = (const float*)d_in[7];
    const float* W1b    = (const float*)d_in[8];
    const float* U1b    = (const float*)d_in[9];
    const float* b1b    = (const float*)d_in[10];
    const float* W2b    = (const float*)d_in[11];
    const float* U2b    = (const float*)d_in[12];
    const float* b2b    = (const float*)d_in[13];
    const float* Wd     = (const float*)d_in[14];
    const float* bd     = (const float*)d_in[15];
    char* ws = (char*)d_ws;

    wconv_kernel<<<12288, 256, 0, stream>>>(W1f, U1f, W1b, U1b, ws + OFF_W1, 24, 256);
    wconv_kernel<<<16384, 256, 0, stream>>>(W2f, U2f, W2b, U2b, ws + OFF_W2, 32, 512);
    gather_x_kernel<<<32768, 256, 0, stream>>>(tokens, emb, ws);
    lstm_persist<<<256, 256, 0, stream>>>(ws, b1f, b2f, b1b, b2b);
    head_kernel<<<NB, 64, 0, stream>>>(ws, Wd, bd, (float*)d_out);
}

// Round 5
// 4212.445 us; speedup vs baseline: 4.9308x; 1.2672x over previous
//
#include <hip/hip_runtime.h>
#include <hip/hip_bf16.h>

// ---------------- problem constants ----------------
#define TSEQ 512
#define NB   64
#define NE   256
#define NH   512
#define NG   2048   // 4*NH

// ---------------- workspace layout (bytes) ----------------
static const size_t OFF_W1  = 0;          // 6,291,456
static const size_t OFF_W2  = 6291456;    // 8,388,608
static const size_t OFF_X   = 14680064;   // 16,777,216  (fragment-linear per t)
static const size_t OFF_H1  = 31457280;   // 2 dir * 4 slot * 64KB = 524,288
static const size_t OFF_H2  = 31981568;   // 524,288
static const size_t OFF_HF  = 32505856;   // 131,072
static const size_t OFF_CNT = 32636928;   // flags: 16 sets * 64 * 4B = 4096

typedef __bf16 v8bf __attribute__((ext_vector_type(8)));
typedef float  v4f  __attribute__((ext_vector_type(4)));
typedef unsigned int v4u __attribute__((ext_vector_type(4)));

#define MFMA16(a_, b_, c_) __builtin_amdgcn_mfma_f32_16x16x32_bf16((a_), (b_), (c_), 0, 0, 0)

// Coherent 16B h-fragment load: two 8B relaxed agent-scope atomic loads.
// Compiler-managed waitcnt (robust even under spills). Fragment-linear layout
// makes the 64 lanes' addresses contiguous 16B-strided -> coalesced.
static __device__ __forceinline__ v8bf load_h8(const __bf16* p) {
    unsigned long long lo = __hip_atomic_load((unsigned long long*)p,     __ATOMIC_RELAXED, __HIP_MEMORY_SCOPE_AGENT);
    unsigned long long hi = __hip_atomic_load((unsigned long long*)p + 1, __ATOMIC_RELAXED, __HIP_MEMORY_SCOPE_AGENT);
    union { unsigned long long q[2]; v8bf v; } u;
    u.q[0] = lo; u.q[1] = hi;
    return u.v;
}

static __device__ __forceinline__ unsigned short bf16_bits(float f) {
    __bf16 b = (__bf16)f;
    return __builtin_bit_cast(unsigned short, b);
}

// ---------------- phase A: weight convert to fragment-linear bf16 ----------------
// dst element id = ((((dir*64+slice)*NC + c)*2 + t)*64 + lane)*8 + j
// holds B[k = c*32 + (lane>>4)*8 + j][n_local = t*16 + (lane&15)]
__global__ void wconv_kernel(const float* __restrict__ Wf, const float* __restrict__ Uf,
                             const float* __restrict__ Wb, const float* __restrict__ Ub,
                             char* __restrict__ dst, int NC, int KX)
{
    int id = blockIdx.x * 256 + threadIdx.x;
    int j    = id & 7;
    int lane = (id >> 3) & 63;
    int t    = (id >> 9) & 1;
    int rest = id >> 10;            // (dir*64+slice)*NC + c
    int c    = rest % NC;
    int ds   = rest / NC;
    int slice = ds & 63;
    int dirr  = ds >> 6;
    int coll = t * 16 + (lane & 15);
    int k    = c * 32 + (lane >> 4) * 8 + j;
    int gate = coll >> 3, jjj = coll & 7;
    int zcol = gate * 512 + slice * 8 + jjj;
    const float* W = dirr ? Wb : Wf;
    const float* U = dirr ? Ub : Uf;
    float v = (k < KX) ? W[(size_t)k * NG + zcol] : U[(size_t)(k - KX) * NG + zcol];
    ((__bf16*)dst)[id] = (__bf16)v;
}

// ---------------- phase A: embedding gather into fragment-linear X + flag zero ----------------
// X element (t, b=m, e) stored at byte: t*32768 + ((e>>3)*64 + m)*16 + (e&7)*2
__global__ void gather_x_kernel(const int* __restrict__ tokens, const float* __restrict__ emb,
                                char* __restrict__ ws)
{
    size_t id = (size_t)blockIdx.x * 256 + threadIdx.x;
    int j  = (int)(id & 7);
    int m  = (int)((id >> 3) & 63);
    int kb = (int)((id >> 9) & 31);
    int t  = (int)(id >> 14);
    int tok = tokens[m * TSEQ + t];
    float v = emb[(size_t)tok * NE + kb * 8 + j];
    ((__bf16*)(ws + OFF_X))[(size_t)t * 16384 + (kb * 64 + m) * 8 + j] = (__bf16)v;
    if (id < 1024) ((int*)(ws + OFF_CNT))[id] = 0;
}

// ---------------- phase B: persistent pipelined recurrence ----------------
// Weights in LDS (fragment-linear, conflict-free lane*16). h fragment-linear
// in WS, accessed with coherent atomic loads/stores (compiler-managed waits).
// Per-wave flags; waves are fully independent -> no __syncthreads in the loop.
template<int LAYER>
__device__ void run_layer(char* __restrict__ ws, const char* __restrict__ smem,
                          int dir, int slice, int tid,
                          const float* __restrict__ bb)
{
    const int lane = tid & 63;
    const int wv   = tid >> 6;
    const int colc = lane & 15;
    const int q    = lane >> 4;
    const int m0   = wv * 16;
    const int jj   = colc & 7;
    const int hcol = slice * 8 + jj;

    __bf16* h1ring = (__bf16*)(ws + OFF_H1 + (size_t)dir * (4 * 65536));
    __bf16* h2ring = (__bf16*)(ws + OFF_H2 + (size_t)dir * (4 * 65536));
    const char* Xfrag = ws + OFF_X;
    __bf16* hfin = (__bf16*)(ws + OFF_HF) + (size_t)dir * (NB * NH);

    int* flags = (int*)(ws + OFF_CNT);
    int* f1p = flags + ((dir * 2 + 0) * 4 + wv) * 64 + lane;   // producer L1, wave wv, slice=lane
    int* f2p = flags + ((dir * 2 + 1) * 4 + wv) * 64 + lane;   // producer L2, wave wv, slice=lane
    int* fown = flags + ((dir * 2 + LAYER) * 4 + wv) * 64 + slice;

    const float bi  = bb[hcol];
    const float bf_ = bb[512 + hcol];
    const float bg  = bb[1024 + hcol];
    const float bo  = bb[1536 + hcol];

    float cst[4] = {0.f, 0.f, 0.f, 0.f};

    // h-fragment element offset for consumer loads (in __bf16 units):
    // ((kb)*64 + (m0+colc)) * 8, kb = 4c+q
    const int aoff = (m0 + colc) * 8;

    #pragma unroll 1
    for (int s = 0; s < TSEQ; ++s) {
        v4f acc0a = {0,0,0,0}, acc1a = {0,0,0,0};
        v4f acc0b = {0,0,0,0}, acc1b = {0,0,0,0};

        // ---- L1: x-part (no step dependency) computed BEFORE the poll ----
        if (LAYER == 0) {
            const int xs = dir ? (TSEQ - 1 - s) : s;
            const char* xb = Xfrag + (size_t)xs * 32768;
            #pragma unroll
            for (int c = 0; c < 8; ++c) {
                v8bf a  = *(const v8bf*)(xb + (((4 * c + q) * 64 + m0 + colc) * 16));
                v8bf w0 = *(const v8bf*)(smem + (c * 2 + 0) * 1024 + lane * 16);
                v8bf w1 = *(const v8bf*)(smem + (c * 2 + 1) * 1024 + lane * 16);
                if (c & 1) { acc0b = MFMA16(a, w0, acc0b); acc1b = MFMA16(a, w1, acc1b); }
                else       { acc0a = MFMA16(a, w0, acc0a); acc1a = MFMA16(a, w1, acc1a); }
            }
        }

        // ---- lane-parallel poll on packed per-wave flags ----
        // L1 step s: f1 >= s (h1[s-1] ready), f2 >= s-3 (ring guard)
        // L2 step s: f1 >= s+1 (h1[s] ready), f2 >= s (h2[s-1] ready)
        {
            const int t1 = LAYER ? s + 1 : s;
            const int t2 = LAYER ? s : s - 3;
            if (t1 > 0) {
                while (true) {
                    int v1 = __hip_atomic_load(f1p, __ATOMIC_RELAXED, __HIP_MEMORY_SCOPE_AGENT);
                    bool ok = (v1 >= t1);
                    if (t2 > 0) {
                        int v2 = __hip_atomic_load(f2p, __ATOMIC_RELAXED, __HIP_MEMORY_SCOPE_AGENT);
                        ok = ok && (v2 >= t2);
                    }
                    if (__all(ok)) break;
                }
            }
        }

        // ---- h-dependent MFMA work (coalesced coherent loads, LDS weights) ----
        if (LAYER == 0) {
            if (s > 0) {
                const __bf16* hb = h1ring + (size_t)((s - 1) & 3) * 32768;
                v8bf ah[16];
                #pragma unroll
                for (int c = 0; c < 16; ++c)
                    ah[c] = load_h8(hb + (4 * c + q) * 512 + aoff);
                __builtin_amdgcn_sched_barrier(0);   // keep the load batch together
                #pragma unroll
                for (int c = 0; c < 16; ++c) {
                    v8bf w0 = *(const v8bf*)(smem + ((8 + c) * 2 + 0) * 1024 + lane * 16);
                    v8bf w1 = *(const v8bf*)(smem + ((8 + c) * 2 + 1) * 1024 + lane * 16);
                    if (c & 1) { acc0b = MFMA16(ah[c], w0, acc0b); acc1b = MFMA16(ah[c], w1, acc1b); }
                    else       { acc0a = MFMA16(ah[c], w0, acc0a); acc1a = MFMA16(ah[c], w1, acc1a); }
                }
            }
        } else {
            const __bf16* hb1 = h1ring + (size_t)(s & 3) * 32768;
            v8bf a0[16], a1[16];
            #pragma unroll
            for (int c = 0; c < 16; ++c)
                a0[c] = load_h8(hb1 + (4 * c + q) * 512 + aoff);
            if (s > 0) {
                const __bf16* hb2 = h2ring + (size_t)((s - 1) & 3) * 32768;
                #pragma unroll
                for (int c = 0; c < 16; ++c)
                    a1[c] = load_h8(hb2 + (4 * c + q) * 512 + aoff);
            }
            __builtin_amdgcn_sched_barrier(0);
            #pragma unroll
            for (int c = 0; c < 16; ++c) {
                v8bf w0 = *(const v8bf*)(smem + (c * 2 + 0) * 1024 + lane * 16);
                v8bf w1 = *(const v8bf*)(smem + (c * 2 + 1) * 1024 + lane * 16);
                if (c & 1) { acc0b = MFMA16(a0[c], w0, acc0b); acc1b = MFMA16(a0[c], w1, acc1b); }
                else       { acc0a = MFMA16(a0[c], w0, acc0a); acc1a = MFMA16(a0[c], w1, acc1a); }
            }
            if (s > 0) {
                #pragma unroll
                for (int c = 0; c < 16; ++c) {
                    v8bf w0 = *(const v8bf*)(smem + ((16 + c) * 2 + 0) * 1024 + lane * 16);
                    v8bf w1 = *(const v8bf*)(smem + ((16 + c) * 2 + 1) * 1024 + lane * 16);
                    if (c & 1) { acc0b = MFMA16(a1[c], w0, acc0b); acc1b = MFMA16(a1[c], w1, acc1b); }
                    else       { acc0a = MFMA16(a1[c], w0, acc0a); acc1a = MFMA16(a1[c], w1, acc1a); }
                }
            }
        }

        v4f z0 = acc0a + acc0b;   // gates i (cols 0-7) / f (cols 8-15)
        v4f z1 = acc1a + acc1b;   // gates g / o

        // ---- gate nonlinearity; lanes col and col^8 exchange ----
        float hv[4];
        #pragma unroll
        for (int r = 0; r < 4; ++r) {
            float p0 = __shfl_xor(z0[r], 8, 64);
            float p1 = __shfl_xor(z1[r], 8, 64);
            float zi, zf, zg, zo;
            if (colc < 8) { zi = z0[r]; zf = p0;    zg = z1[r]; zo = p1;    }
            else          { zi = p0;    zf = z0[r]; zg = p1;    zo = z1[r]; }
            zi += bi; zf += bf_; zg += bg; zo += bo;
            float gi = 1.f / (1.f + __expf(-zi));
            float gf = 1.f / (1.f + __expf(-zf));
            float gg = 1.f - 2.f / (1.f + __expf(2.f * zg));   // tanh
            float go = 1.f / (1.f + __expf(-zo));
            float cn = gf * cst[r] + gi * gg;
            cst[r] = cn;
            float th = 1.f - 2.f / (1.f + __expf(2.f * cn));   // tanh
            hv[r] = go * th;
        }

        // ---- fragment-linear h store: element (m, hcol) at byte (slice*64+m)*16 + jj*2 ----
        __bf16* hd = (LAYER ? h2ring : h1ring) + (size_t)(s & 3) * 32768;
        #pragma unroll
        for (int r = 0; r < 4; ++r) {
            float pv = __shfl_xor(hv[r], 1, 64);
            int m = m0 + q * 4 + r;
            if (((colc & 1) == 0) && (colc < 8)) {
                unsigned val = (unsigned)bf16_bits(hv[r]) | ((unsigned)bf16_bits(pv) << 16);
                __hip_atomic_store((unsigned*)(hd + (slice * 64 + m) * 8 + colc), val,
                                   __ATOMIC_RELAXED, __HIP_MEMORY_SCOPE_AGENT);
            }
            if (LAYER == 1 && s == TSEQ - 1 && colc < 8)
                hfin[(size_t)m * NH + hcol] = (__bf16)hv[r];   // kernel boundary publishes
        }

        // drain this wave's stores (count-independent), then publish flag
        asm volatile("s_waitcnt vmcnt(0)" ::: "memory");
        if (lane == 0)
            __hip_atomic_store(fown, s + 1, __ATOMIC_RELAXED, __HIP_MEMORY_SCOPE_AGENT);
    }
}

__global__ __launch_bounds__(256, 1) void lstm_persist(
    char* __restrict__ ws,
    const float* __restrict__ b1f, const float* __restrict__ b2f,
    const float* __restrict__ b1b, const float* __restrict__ b2b)
{
    const int tid   = threadIdx.x;
    const int bid   = blockIdx.x;       // 256 wgs
    const int dir   = bid >> 7;
    const int layer = (bid >> 6) & 1;
    const int slice = bid & 63;

    const int NC = layer ? 32 : 24;
    const int wbytes = NC * 2048;       // 48KB (L1) / 64KB (L2)

    __shared__ char smem[65536];
    {
        const char* wsrc = ws + (layer ? OFF_W2 : OFF_W1)
                         + (size_t)(dir * 64 + slice) * (size_t)wbytes;
        for (int i = tid * 16; i < wbytes; i += 256 * 16)
            *(uint4*)(smem + i) = *(const uint4*)(wsrc + i);
    }
    __syncthreads();   // staging is cooperative; only barrier in the kernel

    const float* bb = layer ? (dir ? b2b : b2f) : (dir ? b1b : b1f);
    if (layer == 0) run_layer<0>(ws, smem, dir, slice, tid, bb);
    else            run_layer<1>(ws, smem, dir, slice, tid, bb);
}

// ---------------- phase C: dense head [64,1024]@[1024,5]+bd ----------------
__global__ void head_kernel(const char* __restrict__ ws, const float* __restrict__ Wd,
                            const float* __restrict__ bd, float* __restrict__ out)
{
    int b = blockIdx.x;
    int lane = threadIdx.x;   // 64
    const __bf16* hfF = (const __bf16*)(ws + OFF_HF) + (size_t)b * NH;
    const __bf16* hfB = (const __bf16*)(ws + OFF_HF) + (size_t)(NB * NH) + (size_t)b * NH;
    #pragma unroll
    for (int o = 0; o < 5; ++o) {
        float sum = 0.f;
        for (int k = lane; k < 2 * NH; k += 64) {
            float fv = (k < NH) ? (float)hfF[k] : (float)hfB[k - NH];
            sum += fv * Wd[(size_t)k * 5 + o];
        }
        #pragma unroll
        for (int off = 32; off > 0; off >>= 1) sum += __shfl_down(sum, off, 64);
        if (lane == 0) out[b * 5 + o] = sum + bd[o];
    }
}

// ---------------- launch ----------------
extern "C" void kernel_launch(void* const* d_in, const int* in_sizes, int n_in,
                              void* d_out, int out_size, void* d_ws, size_t ws_size,
                              hipStream_t stream)
{
    const int*   tokens = (const int*)  d_in[0];
    const float* emb    = (const float*)d_in[1];
    const float* W1f    = (const float*)d_in[2];
    const float* U1f    = (const float*)d_in[3];
    const float* b1f    = (const float*)d_in[4];
    const float* W2f    = (const float*)d_in[5];
    const float* U2f    = (const float*)d_in[6];
    const float* b2f    = (const float*)d_in[7];
    const float* W1b    = (const float*)d_in[8];
    const float* U1b    = (const float*)d_in[9];
    const float* b1b    = (const float*)d_in[10];
    const float* W2b    = (const float*)d_in[11];
    const float* U2b    = (const float*)d_in[12];
    const float* b2b    = (const float*)d_in[13];
    const float* Wd     = (const float*)d_in[14];
    const float* bd     = (const float*)d_in[15];
    char* ws = (char*)d_ws;

    wconv_kernel<<<12288, 256, 0, stream>>>(W1f, U1f, W1b, U1b, ws + OFF_W1, 24, 256);
    wconv_kernel<<<16384, 256, 0, stream>>>(W2f, U2f, W2b, U2b, ws + OFF_W2, 32, 512);
    gather_x_kernel<<<32768, 256, 0, stream>>>(tokens, emb, ws);
    lstm_persist<<<256, 256, 0, stream>>>(ws, b1f, b2f, b1b, b2b);
    head_kernel<<<NB, 64, 0, stream>>>(ws, Wd, bd, (float*)d_out);
}

// Round 8
// 3614.964 us; speedup vs baseline: 5.7458x; 1.1653x over previous
//
#include <hip/hip_runtime.h>
#include <hip/hip_bf16.h>

// ---------------- problem constants ----------------
#define TSEQ 512
#define NB   64
#define NE   256
#define NH   512
#define NG   2048   // 4*NH

// ---------------- workspace layout (bytes) ----------------
static const size_t OFF_W1  = 0;          // 6,291,456
static const size_t OFF_W2  = 6291456;    // 8,388,608
static const size_t OFF_X   = 14680064;   // 16,777,216  (fragment-linear per t)
static const size_t OFF_H1  = 31457280;   // 2 dir * 4 slot * 64KB = 524,288
static const size_t OFF_H2  = 31981568;   // 524,288
static const size_t OFF_HF  = 32505856;   // 131,072
static const size_t OFF_CNT = 32636928;   // tags: 4 sets * 16 rep * 256 * 4B = 64 KB

typedef __bf16 v8bf __attribute__((ext_vector_type(8)));
typedef float  v4f  __attribute__((ext_vector_type(4)));

#define MFMA16(a_, b_, c_) __builtin_amdgcn_mfma_f32_16x16x32_bf16((a_), (b_), (c_), 0, 0, 0)

// Coherent 16B h-fragment load: two 8B relaxed agent-scope atomic loads.
// Compiler-managed waitcnt (robust under spills). Fragment-linear layout makes
// the 64 lanes' addresses contiguous -> coalesced.
static __device__ __forceinline__ v8bf load_h8(const __bf16* p) {
    unsigned long long lo = __hip_atomic_load((unsigned long long*)p,     __ATOMIC_RELAXED, __HIP_MEMORY_SCOPE_AGENT);
    unsigned long long hi = __hip_atomic_load((unsigned long long*)p + 1, __ATOMIC_RELAXED, __HIP_MEMORY_SCOPE_AGENT);
    union { unsigned long long q[2]; v8bf v; } u;
    u.q[0] = lo; u.q[1] = hi;
    return u.v;
}

static __device__ __forceinline__ unsigned short bf16_bits(float f) {
    __bf16 b = (__bf16)f;
    return __builtin_bit_cast(unsigned short, b);
}

// ---------------- phase A: weight convert to fragment-linear bf16 ----------------
__global__ void wconv_kernel(const float* __restrict__ Wf, const float* __restrict__ Uf,
                             const float* __restrict__ Wb, const float* __restrict__ Ub,
                             char* __restrict__ dst, int NC, int KX)
{
    int id = blockIdx.x * 256 + threadIdx.x;
    int j    = id & 7;
    int lane = (id >> 3) & 63;
    int t    = (id >> 9) & 1;
    int rest = id >> 10;            // (dir*64+slice)*NC + c
    int c    = rest % NC;
    int ds   = rest / NC;
    int slice = ds & 63;
    int dirr  = ds >> 6;
    int coll = t * 16 + (lane & 15);
    int k    = c * 32 + (lane >> 4) * 8 + j;
    int gate = coll >> 3, jjj = coll & 7;
    int zcol = gate * 512 + slice * 8 + jjj;
    const float* W = dirr ? Wb : Wf;
    const float* U = dirr ? Ub : Uf;
    float v = (k < KX) ? W[(size_t)k * NG + zcol] : U[(size_t)(k - KX) * NG + zcol];
    ((__bf16*)dst)[id] = (__bf16)v;
}

// ---------------- phase A: embedding gather into fragment-linear X + tag zero ----------------
// X element (t, b=m, e) stored at byte: t*32768 + ((e>>3)*64 + m)*16 + (e&7)*2
__global__ void gather_x_kernel(const int* __restrict__ tokens, const float* __restrict__ emb,
                                char* __restrict__ ws)
{
    size_t id = (size_t)blockIdx.x * 256 + threadIdx.x;
    int j  = (int)(id & 7);
    int m  = (int)((id >> 3) & 63);
    int kb = (int)((id >> 9) & 31);
    int t  = (int)(id >> 14);
    int tok = tokens[m * TSEQ + t];
    float v = emb[(size_t)tok * NE + kb * 8 + j];
    ((__bf16*)(ws + OFF_X))[(size_t)t * 16384 + (kb * 64 + m) * 8 + j] = (__bf16)v;
    if (id < 16384) ((int*)(ws + OFF_CNT))[id] = 0;    // all tag replicas
}

// ---------------- phase B: persistent pipelined recurrence ----------------
// Byte-identical to the proven R5 structure (ring depth 4, slot stride 32768
// bf16) EXCEPT the sync tags are replicated x16: producers publish to 16
// replica lines, each consumer wave polls replica (4*slice+wv)&15 — spreads
// poller traffic over 16 line-sets instead of hammering 2 hot lines.
template<int LAYER>
__device__ void run_layer(char* __restrict__ ws, const char* __restrict__ smem,
                          int dir, int slice, int tid,
                          const float* __restrict__ bb)
{
    const int lane = tid & 63;
    const int wv   = tid >> 6;
    const int colc = lane & 15;
    const int q    = lane >> 4;
    const int m0   = wv * 16;
    const int jj   = colc & 7;
    const int hcol = slice * 8 + jj;

    __bf16* h1ring = (__bf16*)(ws + OFF_H1 + (size_t)dir * (4 * 65536));
    __bf16* h2ring = (__bf16*)(ws + OFF_H2 + (size_t)dir * (4 * 65536));
    const char* Xfrag = ws + OFF_X;
    __bf16* hfin = (__bf16*)(ws + OFF_HF) + (size_t)dir * (NB * NH);

    // tags: T[(dir*2+layer)*4096 + rep*256 + wv*64 + slice]
    int* T = (int*)(ws + OFF_CNT);
    const int rep = ((slice << 2) | wv) & 15;
    int* p1   = T + (dir * 2 + 0) * 4096 + rep * 256 + wv * 64 + lane;   // poll L1 producers (wave wv, slice=lane)
    int* p2   = T + (dir * 2 + 1) * 4096 + rep * 256 + wv * 64 + lane;   // poll L2 producers
    int* ownb = T + (dir * 2 + LAYER) * 4096;                             // publish base

    const float bi  = bb[hcol];
    const float bf_ = bb[512 + hcol];
    const float bg  = bb[1024 + hcol];
    const float bo  = bb[1536 + hcol];

    float cst[4] = {0.f, 0.f, 0.f, 0.f};

    // h-fragment element offset for consumer loads (in __bf16 units)
    const int aoff = (m0 + colc) * 8;

    #pragma unroll 1
    for (int s = 0; s < TSEQ; ++s) {
        v4f acc0a = {0,0,0,0}, acc1a = {0,0,0,0};
        v4f acc0b = {0,0,0,0}, acc1b = {0,0,0,0};

        // ---- L1: x-part (no step dependency) computed BEFORE the poll ----
        if (LAYER == 0) {
            const int xs = dir ? (TSEQ - 1 - s) : s;
            const char* xb = Xfrag + (size_t)xs * 32768;
            #pragma unroll
            for (int c = 0; c < 8; ++c) {
                v8bf a  = *(const v8bf*)(xb + (((4 * c + q) * 64 + m0 + colc) * 16));
                v8bf w0 = *(const v8bf*)(smem + (c * 2 + 0) * 1024 + lane * 16);
                v8bf w1 = *(const v8bf*)(smem + (c * 2 + 1) * 1024 + lane * 16);
                if (c & 1) { acc0b = MFMA16(a, w0, acc0b); acc1b = MFMA16(a, w1, acc1b); }
                else       { acc0a = MFMA16(a, w0, acc0a); acc1a = MFMA16(a, w1, acc1a); }
            }
        }

        // ---- lane-parallel poll on replicated per-wave tags ----
        // L1 step s: p1 >= s (h1[s-1] ready), p2 >= s-3 (ring guard)
        // L2 step s: p1 >= s+1 (h1[s] ready), p2 >= s (h2[s-1] ready)
        {
            const int t1 = LAYER ? s + 1 : s;
            const int t2 = LAYER ? s : s - 3;
            if (t1 > 0) {
                while (true) {
                    int v1 = __hip_atomic_load(p1, __ATOMIC_RELAXED, __HIP_MEMORY_SCOPE_AGENT);
                    bool ok = (v1 >= t1);
                    if (t2 > 0) {
                        int v2 = __hip_atomic_load(p2, __ATOMIC_RELAXED, __HIP_MEMORY_SCOPE_AGENT);
                        ok = ok && (v2 >= t2);
                    }
                    if (__all(ok)) break;
                }
            }
        }

        // ---- h-dependent MFMA work (coalesced coherent loads, LDS weights) ----
        if (LAYER == 0) {
            if (s > 0) {
                const __bf16* hb = h1ring + (size_t)((s - 1) & 3) * 32768;
                v8bf ah[16];
                #pragma unroll
                for (int c = 0; c < 16; ++c)
                    ah[c] = load_h8(hb + (4 * c + q) * 512 + aoff);
                __builtin_amdgcn_sched_barrier(0);   // keep the load batch together
                #pragma unroll
                for (int c = 0; c < 16; ++c) {
                    v8bf w0 = *(const v8bf*)(smem + ((8 + c) * 2 + 0) * 1024 + lane * 16);
                    v8bf w1 = *(const v8bf*)(smem + ((8 + c) * 2 + 1) * 1024 + lane * 16);
                    if (c & 1) { acc0b = MFMA16(ah[c], w0, acc0b); acc1b = MFMA16(ah[c], w1, acc1b); }
                    else       { acc0a = MFMA16(ah[c], w0, acc0a); acc1a = MFMA16(ah[c], w1, acc1a); }
                }
            }
        } else {
            const __bf16* hb1 = h1ring + (size_t)(s & 3) * 32768;
            v8bf a0[16], a1[16];
            #pragma unroll
            for (int c = 0; c < 16; ++c)
                a0[c] = load_h8(hb1 + (4 * c + q) * 512 + aoff);
            if (s > 0) {
                const __bf16* hb2 = h2ring + (size_t)((s - 1) & 3) * 32768;
                #pragma unroll
                for (int c = 0; c < 16; ++c)
                    a1[c] = load_h8(hb2 + (4 * c + q) * 512 + aoff);
            }
            __builtin_amdgcn_sched_barrier(0);
            #pragma unroll
            for (int c = 0; c < 16; ++c) {
                v8bf w0 = *(const v8bf*)(smem + (c * 2 + 0) * 1024 + lane * 16);
                v8bf w1 = *(const v8bf*)(smem + (c * 2 + 1) * 1024 + lane * 16);
                if (c & 1) { acc0b = MFMA16(a0[c], w0, acc0b); acc1b = MFMA16(a0[c], w1, acc1b); }
                else       { acc0a = MFMA16(a0[c], w0, acc0a); acc1a = MFMA16(a0[c], w1, acc1a); }
            }
            if (s > 0) {
                #pragma unroll
                for (int c = 0; c < 16; ++c) {
                    v8bf w0 = *(const v8bf*)(smem + ((16 + c) * 2 + 0) * 1024 + lane * 16);
                    v8bf w1 = *(const v8bf*)(smem + ((16 + c) * 2 + 1) * 1024 + lane * 16);
                    if (c & 1) { acc0b = MFMA16(a1[c], w0, acc0b); acc1b = MFMA16(a1[c], w1, acc1b); }
                    else       { acc0a = MFMA16(a1[c], w0, acc0a); acc1a = MFMA16(a1[c], w1, acc1a); }
                }
            }
        }

        v4f z0 = acc0a + acc0b;   // gates i (cols 0-7) / f (cols 8-15)
        v4f z1 = acc1a + acc1b;   // gates g / o

        // ---- gate nonlinearity; lanes col and col^8 exchange ----
        float hv[4];
        #pragma unroll
        for (int r = 0; r < 4; ++r) {
            float p0 = __shfl_xor(z0[r], 8, 64);
            float p1 = __shfl_xor(z1[r], 8, 64);
            float zi, zf, zg, zo;
            if (colc < 8) { zi = z0[r]; zf = p0;    zg = z1[r]; zo = p1;    }
            else          { zi = p0;    zf = z0[r]; zg = p1;    zo = z1[r]; }
            zi += bi; zf += bf_; zg += bg; zo += bo;
            float gi = 1.f / (1.f + __expf(-zi));
            float gf = 1.f / (1.f + __expf(-zf));
            float gg = 1.f - 2.f / (1.f + __expf(2.f * zg));   // tanh
            float go = 1.f / (1.f + __expf(-zo));
            float cn = gf * cst[r] + gi * gg;
            cst[r] = cn;
            float th = 1.f - 2.f / (1.f + __expf(2.f * cn));   // tanh
            hv[r] = go * th;
        }

        // ---- fragment-linear h store: element (m, hcol) at byte (slice*64+m)*16 + jj*2 ----
        __bf16* hd = (LAYER ? h2ring : h1ring) + (size_t)(s & 3) * 32768;
        #pragma unroll
        for (int r = 0; r < 4; ++r) {
            float pv = __shfl_xor(hv[r], 1, 64);
            int m = m0 + q * 4 + r;
            if (((colc & 1) == 0) && (colc < 8)) {
                unsigned val = (unsigned)bf16_bits(hv[r]) | ((unsigned)bf16_bits(pv) << 16);
                __hip_atomic_store((unsigned*)(hd + (slice * 64 + m) * 8 + colc), val,
                                   __ATOMIC_RELAXED, __HIP_MEMORY_SCOPE_AGENT);
            }
            if (LAYER == 1 && s == TSEQ - 1 && colc < 8)
                hfin[(size_t)m * NH + hcol] = (__bf16)hv[r];   // kernel boundary publishes
        }

        // drain this wave's stores (count-independent), then publish tag to 16 replicas
        asm volatile("s_waitcnt vmcnt(0)" ::: "memory");
        if (lane < 16)
            __hip_atomic_store(ownb + lane * 256 + wv * 64 + slice, s + 1,
                               __ATOMIC_RELAXED, __HIP_MEMORY_SCOPE_AGENT);
    }
}

__global__ __launch_bounds__(256, 1) void lstm_persist(
    char* __restrict__ ws,
    const float* __restrict__ b1f, const float* __restrict__ b2f,
    const float* __restrict__ b1b, const float* __restrict__ b2b)
{
    const int tid   = threadIdx.x;
    const int bid   = blockIdx.x;       // 256 wgs
    const int dir   = bid >> 7;
    const int layer = (bid >> 6) & 1;
    const int slice = bid & 63;

    const int NC = layer ? 32 : 24;
    const int wbytes = NC * 2048;       // 48KB (L1) / 64KB (L2)

    __shared__ char smem[65536];
    {
        const char* wsrc = ws + (layer ? OFF_W2 : OFF_W1)
                         + (size_t)(dir * 64 + slice) * (size_t)wbytes;
        for (int i = tid * 16; i < wbytes; i += 256 * 16)
            *(uint4*)(smem + i) = *(const uint4*)(wsrc + i);
    }
    __syncthreads();   // staging is cooperative; only barrier in the kernel

    const float* bb = layer ? (dir ? b2b : b2f) : (dir ? b1b : b1f);
    if (layer == 0) run_layer<0>(ws, smem, dir, slice, tid, bb);
    else            run_layer<1>(ws, smem, dir, slice, tid, bb);
}

// ---------------- phase C: dense head [64,1024]@[1024,5]+bd ----------------
__global__ void head_kernel(const char* __restrict__ ws, const float* __restrict__ Wd,
                            const float* __restrict__ bd, float* __restrict__ out)
{
    int b = blockIdx.x;
    int lane = threadIdx.x;   // 64
    const __bf16* hfF = (const __bf16*)(ws + OFF_HF) + (size_t)b * NH;
    const __bf16* hfB = (const __bf16*)(ws + OFF_HF) + (size_t)(NB * NH) + (size_t)b * NH;
    #pragma unroll
    for (int o = 0; o < 5; ++o) {
        float sum = 0.f;
        for (int k = lane; k < 2 * NH; k += 64) {
            float fv = (k < NH) ? (float)hfF[k] : (float)hfB[k - NH];
            sum += fv * Wd[(size_t)k * 5 + o];
        }
        #pragma unroll
        for (int off = 32; off > 0; off >>= 1) sum += __shfl_down(sum, off, 64);
        if (lane == 0) out[b * 5 + o] = sum + bd[o];
    }
}

// ---------------- launch ----------------
extern "C" void kernel_launch(void* const* d_in, const int* in_sizes, int n_in,
                              void* d_out, int out_size, void* d_ws, size_t ws_size,
                              hipStream_t stream)
{
    const int*   tokens = (const int*)  d_in[0];
    const float* emb    = (const float*)d_in[1];
    const float* W1f    = (const float*)d_in[2];
    const float* U1f    = (const float*)d_in[3];
    const float* b1f    = (const float*)d_in[4];
    const float* W2f    = (const float*)d_in[5];
    const float* U2f    = (const float*)d_in[6];
    const float* b2f    = (const float*)d_in[7];
    const float* W1b    = (const float*)d_in[8];
    const float* U1b    = (const float*)d_in[9];
    const float* b1b    = (const float*)d_in[10];
    const float* W2b    = (const float*)d_in[11];
    const float* U2b    = (const float*)d_in[12];
    const float* b2b    = (const float*)d_in[13];
    const float* Wd     = (const float*)d_in[14];
    const float* bd     = (const float*)d_in[15];
    char* ws = (char*)d_ws;

    wconv_kernel<<<12288, 256, 0, stream>>>(W1f, U1f, W1b, U1b, ws + OFF_W1, 24, 256);
    wconv_kernel<<<16384, 256, 0, stream>>>(W2f, U2f, W2b, U2b, ws + OFF_W2, 32, 512);
    gather_x_kernel<<<32768, 256, 0, stream>>>(tokens, emb, ws);
    lstm_persist<<<256, 256, 0, stream>>>(ws, b1f, b2f, b1b, b2b);
    head_kernel<<<NB, 64, 0, stream>>>(ws, Wd, bd, (float*)d_out);
}